// Round 7
// baseline (266.387 us; speedup 1.0000x reference)
//
#include <hip/hip_runtime.h>
#include <math.h>

#define NN 50000
#define EE 600000
#define DD 128
#define GG 64
#define NCLS 10
#define PCHUNK 64
#define NTILE (NN / 16)            // 3125 row-tiles, exact
#define NBUK 196                   // buckets of 256 dst nodes (dst>>8)
#define BSTRIDE 4096               // slots per bucket (mean 3072, sigma 55)
#define EPB ((EE + 255) / 256)     // 2344 edges per pass-1 block

typedef __attribute__((ext_vector_type(8))) __bf16 bf16x8;
typedef __attribute__((ext_vector_type(8))) unsigned short u16x8;
typedef __attribute__((ext_vector_type(4))) float f32x4;
typedef __attribute__((ext_vector_type(2))) float f32x2;

#define LGKM_FENCE() asm volatile("s_waitcnt lgkmcnt(0)" ::: "memory")
#define SCHED_FENCE() __builtin_amdgcn_sched_barrier(0)

__device__ __forceinline__ unsigned short f2bf(float f) {
    unsigned int u = __float_as_uint(f);
    u += 0x7fff + ((u >> 16) & 1);     // round-to-nearest-even
    return (unsigned short)(u >> 16);
}

__device__ __forceinline__ float bf2f(unsigned short h) {
    return __uint_as_float(((unsigned int)h) << 16);
}

// dword-wise bf16 pair unpack: 1 VALU op per element
__device__ __forceinline__ float lo16(unsigned int u) { return __uint_as_float(u << 16); }
__device__ __forceinline__ float hi16(unsigned int u) { return __uint_as_float(u & 0xffff0000u); }

// ------- fused prep: zero bucketcnt/gsum + wt convert + x fp32->bf16 --------

__global__ __launch_bounds__(256) void prep_kernel(
    const float* __restrict__ wq, const float* __restrict__ wk,
    const float* __restrict__ wv, const float* __restrict__ ws,
    const float* __restrict__ x, unsigned short* __restrict__ xb,
    unsigned short* __restrict__ wt,
    int* __restrict__ bucketcnt, float* __restrict__ gsum) {
    int tid = blockIdx.x * 256 + threadIdx.x;
    int TOT = gridDim.x * 256;
    if (tid < 256) bucketcnt[tid] = 0;
    for (int i = tid; i < GG * DD + GG; i += TOT) gsum[i] = 0.f;
    for (int i = tid; i < 2 * 4 * 16384; i += TOT) {
        int k = i & 127;
        int n = (i >> 7) & 127;
        int lm = i >> 14;
        int l = lm >> 2, m = lm & 3;
        const float* w = (m == 0) ? wq : (m == 1) ? wk : (m == 2) ? wv : ws;
        wt[i] = f2bf(w[l * 16384 + k * 128 + n]);
    }
    // x: 50000*128 fp32 -> bf16, 8 elems per thread-iter, fully coalesced
    for (int i = tid; i < NN * DD / 8; i += TOT) {
        const float* px = x + (size_t)i * 8;
        float4 f0 = *(const float4*)px;
        float4 f1 = *(const float4*)(px + 4);
        u16x8 o;
        o[0] = f2bf(f0.x); o[1] = f2bf(f0.y); o[2] = f2bf(f0.z); o[3] = f2bf(f0.w);
        o[4] = f2bf(f1.x); o[5] = f2bf(f1.y); o[6] = f2bf(f1.z); o[7] = f2bf(f1.w);
        *(u16x8*)(xb + (size_t)i * 8) = o;
    }
}

// ---------------- CSR pass 1: bucket by dst>>8 ------------------------------

__global__ __launch_bounds__(1024) void bucket_kernel(
    const int* __restrict__ src, const int* __restrict__ dst,
    int* __restrict__ bucketcnt, int2* __restrict__ bedge) {
    __shared__ int hist[256];
    __shared__ int base[256];
    int t = threadIdx.x;
    if (t < 256) hist[t] = 0;
    __syncthreads();
    int e0 = blockIdx.x * EPB;
    int eend = min(e0 + EPB, EE);

    int b0 = -1, b1 = -1, b2 = -1;
    int sl0 = 0, sl1 = 0, sl2 = 0;
    int s0 = 0, s1 = 0, s2 = 0, d0 = 0, d1 = 0, d2 = 0;
    int i = e0 + t;
    if (i < eend) { d0 = dst[i]; s0 = src[i]; b0 = d0 >> 8; sl0 = atomicAdd(&hist[b0], 1); }
    i += 1024;
    if (i < eend) { d1 = dst[i]; s1 = src[i]; b1 = d1 >> 8; sl1 = atomicAdd(&hist[b1], 1); }
    i += 1024;
    if (i < eend) { d2 = dst[i]; s2 = src[i]; b2 = d2 >> 8; sl2 = atomicAdd(&hist[b2], 1); }
    __syncthreads();

    if (t < 256) {
        int h = hist[t];
        base[t] = h ? atomicAdd(&bucketcnt[t], h) : 0;
    }
    __syncthreads();

    if (b0 >= 0) bedge[b0 * BSTRIDE + base[b0] + sl0] = make_int2(s0, d0);
    if (b1 >= 0) bedge[b1 * BSTRIDE + base[b1] + sl1] = make_int2(s1, d1);
    if (b2 >= 0) bedge[b2 * BSTRIDE + base[b2] + sl2] = make_int2(s2, d2);
}

// ---------------- CSR pass 2: per-bucket node sort -> indptr + esrc ---------

__global__ __launch_bounds__(1024) void bsort_kernel(
    const int* __restrict__ bucketcnt, const int2* __restrict__ bedge,
    int* __restrict__ indptr, int* __restrict__ esrc) {
    __shared__ int buf[256];
    __shared__ int cur[256];
    int b = blockIdx.x;
    int t = threadIdx.x;

    if (t < 256) buf[t] = (t < NBUK) ? bucketcnt[t] : 0;
    __syncthreads();
    if (t < 64) {
        int carry = 0;
        #pragma unroll
        for (int c = 0; c < 4; ++c) {
            int v = buf[c * 64 + t];
            int x = v;
            #pragma unroll
            for (int off = 1; off < 64; off <<= 1) {
                int y = __shfl_up(x, off);
                if (t >= off) x += y;
            }
            cur[c * 64 + t] = carry + x - v;
            carry += __shfl(x, 63);
        }
    }
    __syncthreads();
    int count = buf[b];
    int bstart = cur[b];
    int node0 = b << 8;
    int nn = min(256, NN - node0);
    if (b == 0 && t == 0) indptr[NN] = EE;
    __syncthreads();
    if (t < 256) buf[t] = 0;
    __syncthreads();

    const int2* be = bedge + (size_t)b * BSTRIDE;
    for (int i2 = t; i2 < count; i2 += 1024)
        atomicAdd(&buf[be[i2].y - node0], 1);
    __syncthreads();

    if (t < 64) {
        int carry = 0;
        #pragma unroll
        for (int c = 0; c < 4; ++c) {
            int v = buf[c * 64 + t];
            int x = v;
            #pragma unroll
            for (int off = 1; off < 64; off <<= 1) {
                int y = __shfl_up(x, off);
                if (t >= off) x += y;
            }
            cur[c * 64 + t] = carry + x - v;
            carry += __shfl(x, 63);
        }
    }
    __syncthreads();
    if (t < nn) indptr[node0 + t] = bstart + cur[t];
    __syncthreads();

    for (int i2 = t; i2 < count; i2 += 1024) {
        int2 e = be[i2];
        int slot = atomicAdd(&cur[e.y - node0], 1);
        esrc[bstart + slot] = e.x;
    }
}

// ------- persistent paired-mat MFMA GEMM, fp8 kv epilogue, pipelined --------
// (unchanged from R6; R5 pre-commit: gemm theories exhausted, hands off)

__global__ __launch_bounds__(256, 2) void gemm_mfma(
    const unsigned short* __restrict__ xin,     // bf16 [NN][128]
    const unsigned short* __restrict__ wt,      // [4][128][128] bf16, n-major
    const float* __restrict__ bq, const float* __restrict__ bk,
    const float* __restrict__ bv, const float* __restrict__ bs,
    unsigned short* __restrict__ qb, unsigned short* __restrict__ sb,
    unsigned char* __restrict__ kv8) {
    // [mi][row][col] u16, row stride 136 (272B)
    __shared__ __align__(16) unsigned short stg[2][16][136];

    int wid = threadIdx.x >> 6;        // 0..3
    int lane = threadIdx.x & 63;
    int typeB = blockIdx.x & 1;        // 0: q/s block, 1: k/v block
    int mi = wid >> 1;                 // mat index within type
    int ch = wid & 1;                  // 64-col half
    int mat = typeB ? (mi ? 2 : 1) : (mi ? 3 : 0);
    int wseq = blockIdx.x >> 1;        // 0..255
    int lr = lane & 15, quad = lane >> 4;

    const unsigned short* wm_ = wt + mat * 16384;
    const float* bias = (mat == 0) ? bq : (mat == 1) ? bk : (mat == 2) ? bv : bs;

    bf16x8 bfr[4][4];
    #pragma unroll
    for (int ks = 0; ks < 4; ++ks)
        #pragma unroll
        for (int tn = 0; tn < 4; ++tn)
            bfr[ks][tn] = *(const bf16x8*)(wm_ + (ch * 64 + tn * 16 + lr) * 128
                                               + ks * 32 + quad * 8);
    float bcol[4];
    #pragma unroll
    for (int tn = 0; tn < 4; ++tn) bcol[tn] = bias[ch * 64 + tn * 16 + lr];

    int t = threadIdx.x;
    int rr = t >> 4;                   // epilogue row 0..15
    int cj = t & 15;                   // epilogue chunk 0..15

    bf16x8 bufA[4], bufB[4];

    auto load_t = [&](bf16x8 (&b)[4], int tl) {
        const unsigned short* p = xin + (size_t)(tl * 16 + lr) * DD + quad * 8;
        #pragma unroll
        for (int ks = 0; ks < 4; ++ks)
            b[ks] = *(const bf16x8*)(p + ks * 32);
    };

    auto compute_store = [&](bf16x8 (&b)[4], int tile) {
        int row0 = tile * 16;
        f32x4 acc[4];
        #pragma unroll
        for (int tn = 0; tn < 4; ++tn) acc[tn] = (f32x4){0.f, 0.f, 0.f, 0.f};
        #pragma unroll
        for (int ks = 0; ks < 4; ++ks)
            #pragma unroll
            for (int tn = 0; tn < 4; ++tn)
                acc[tn] = __builtin_amdgcn_mfma_f32_16x16x32_bf16(
                    b[ks], bfr[ks][tn], acc[tn], 0, 0, 0);

        // C/D layout: col = lane&15 (+tn*16), row = quad*4 + reg
        #pragma unroll
        for (int tn = 0; tn < 4; ++tn)
            #pragma unroll
            for (int r = 0; r < 4; ++r)
                stg[mi][quad * 4 + r][ch * 64 + tn * 16 + lr] = f2bf(acc[tn][r] + bcol[tn]);
        SCHED_FENCE();
        LGKM_FENCE();                  // ds_writes visible before signaling
        __builtin_amdgcn_s_barrier();
        SCHED_FENCE();

        if (!typeB) {
            // q + s: 16B/thread each, 4KB contiguous per buffer
            uint4 vq = *(const uint4*)&stg[0][rr][cj * 8];
            *(uint4*)(qb + (size_t)(row0 + rr) * 128 + cj * 8) = vq;
            uint4 vs = *(const uint4*)&stg[1][rr][cj * 8];
            *(uint4*)(sb + (size_t)(row0 + rr) * 128 + cj * 8) = vs;
        } else {
            // kv8 row (256B = 16 chunks): chunk j = [k fp8 8j..8j+7 | v fp8 8j..8j+7]
            uint4 kk = *(const uint4*)&stg[0][rr][cj * 8];
            uint4 vv = *(const uint4*)&stg[1][rr][cj * 8];
            unsigned int w0 = __builtin_amdgcn_cvt_pk_fp8_f32(lo16(kk.x), hi16(kk.x), 0, false);
            w0 = __builtin_amdgcn_cvt_pk_fp8_f32(lo16(kk.y), hi16(kk.y), w0, true);
            unsigned int w1 = __builtin_amdgcn_cvt_pk_fp8_f32(lo16(kk.z), hi16(kk.z), 0, false);
            w1 = __builtin_amdgcn_cvt_pk_fp8_f32(lo16(kk.w), hi16(kk.w), w1, true);
            unsigned int w2 = __builtin_amdgcn_cvt_pk_fp8_f32(lo16(vv.x), hi16(vv.x), 0, false);
            w2 = __builtin_amdgcn_cvt_pk_fp8_f32(lo16(vv.y), hi16(vv.y), w2, true);
            unsigned int w3 = __builtin_amdgcn_cvt_pk_fp8_f32(lo16(vv.z), hi16(vv.z), 0, false);
            w3 = __builtin_amdgcn_cvt_pk_fp8_f32(lo16(vv.w), hi16(vv.w), w3, true);
            *(uint4*)(kv8 + (size_t)(row0 + rr) * 256 + cj * 16) = make_uint4(w0, w1, w2, w3);
        }
        SCHED_FENCE();
        LGKM_FENCE();                  // ds_reads done before stg overwrite
        __builtin_amdgcn_s_barrier();
        SCHED_FENCE();
    };

    int tile = wseq;
    load_t(bufA, tile);
    for (;;) {
        int t2 = tile + 256;
        if (t2 < NTILE) load_t(bufB, t2);       // in flight across barriers
        compute_store(bufA, tile);
        if (t2 >= NTILE) break;
        tile = t2;
        int t3 = tile + 256;
        if (t3 < NTILE) load_t(bufA, t3);
        compute_store(bufB, tile);
        if (t3 >= NTILE) break;
        tile = t3;
    }
}

// ---------------- fused online-softmax attention (fp8 kv) -------------------
// R23: 4 groups x 16 lanes -> 8 groups x 8 lanes. Regime: gather-latency-
// bound serial chain (deg~12 Poisson, 256B row gather per edge, L2/L3-hit
// latency). Serial depth ceil(deg/4)~3.2 -> ceil(deg/8)~1.9; outstanding
// loads per wave 8 -> 16 (each lane now covers chunks j and j+8 = 32B).
// Dot reduce: 3 shfl (masks 4,2,1) within group; final cross-group reduce
// masks 8,16,32. Math order per channel identical.

__global__ __launch_bounds__(256) void attn_kernel(
    const unsigned short* __restrict__ qb, const unsigned char* __restrict__ kv8,
    const unsigned short* __restrict__ sb,
    const int* __restrict__ indptr, const int* __restrict__ esrc,
    unsigned short* __restrict__ hout, int n) {
    int node = (int)((blockIdx.x * blockDim.x + threadIdx.x) >> 6);
    int lane = threadIdx.x & 63;
    if (node >= n) return;
    int g = lane >> 3, j = lane & 7;

    u16x8 qA = *(const u16x8*)(qb + (size_t)node * DD + j * 8);
    u16x8 qB = *(const u16x8*)(qb + (size_t)node * DD + 64 + j * 8);
    float qf[16];
    #pragma unroll
    for (int c = 0; c < 8; ++c) { qf[c] = bf2f(qA[c]); qf[8 + c] = bf2f(qB[c]); }

    int beg = indptr[node], end = indptr[node + 1];

    float m = -3.0e38f, den = 0.f;
    float acc[16];
    #pragma unroll
    for (int c = 0; c < 16; ++c) acc[c] = 0.f;

    int e = beg + g;
    if (e < end) {
        int sidx = esrc[e];
        int en = e + 8;
        int sn = (en < end) ? esrc[en] : 0;          // index 1 ahead (resident)
        uint4 kvA = *(const uint4*)(kv8 + (size_t)sidx * 256 + j * 16);
        uint4 kvB = *(const uint4*)(kv8 + (size_t)sidx * 256 + 128 + j * 16);
        for (;;) {
            bool haven = en < end;
            int en2 = en + 8;
            int sn2 = (en2 < end) ? esrc[en2] : 0;   // index 2 ahead (loading)
            uint4 kvnA, kvnB;
            if (haven) {
                kvnA = *(const uint4*)(kv8 + (size_t)sn * 256 + j * 16);
                kvnB = *(const uint4*)(kv8 + (size_t)sn * 256 + 128 + j * 16);
            }
            f32x2 a01 = __builtin_amdgcn_cvt_pk_f32_fp8(kvA.x, false);
            f32x2 a23 = __builtin_amdgcn_cvt_pk_f32_fp8(kvA.x, true);
            f32x2 a45 = __builtin_amdgcn_cvt_pk_f32_fp8(kvA.y, false);
            f32x2 a67 = __builtin_amdgcn_cvt_pk_f32_fp8(kvA.y, true);
            f32x2 b01 = __builtin_amdgcn_cvt_pk_f32_fp8(kvB.x, false);
            f32x2 b23 = __builtin_amdgcn_cvt_pk_f32_fp8(kvB.x, true);
            f32x2 b45 = __builtin_amdgcn_cvt_pk_f32_fp8(kvB.y, false);
            f32x2 b67 = __builtin_amdgcn_cvt_pk_f32_fp8(kvB.y, true);
            float p_;
            p_ = qf[0] * a01.x;
            p_ = fmaf(qf[1], a01.y, p_);
            p_ = fmaf(qf[2], a23.x, p_);
            p_ = fmaf(qf[3], a23.y, p_);
            p_ = fmaf(qf[4], a45.x, p_);
            p_ = fmaf(qf[5], a45.y, p_);
            p_ = fmaf(qf[6], a67.x, p_);
            p_ = fmaf(qf[7], a67.y, p_);
            p_ = fmaf(qf[8], b01.x, p_);
            p_ = fmaf(qf[9], b01.y, p_);
            p_ = fmaf(qf[10], b23.x, p_);
            p_ = fmaf(qf[11], b23.y, p_);
            p_ = fmaf(qf[12], b45.x, p_);
            p_ = fmaf(qf[13], b45.y, p_);
            p_ = fmaf(qf[14], b67.x, p_);
            p_ = fmaf(qf[15], b67.y, p_);
            p_ += __shfl_xor(p_, 4);
            p_ += __shfl_xor(p_, 2);
            p_ += __shfl_xor(p_, 1);
            float score = p_ * 0.088388347648318447f;   // 1/sqrt(128)
            float mn = fmaxf(m, score);
            float scale = __expf(m - mn);
            float pe = __expf(score - mn);
            den = den * scale + pe;
            f32x2 va01 = __builtin_amdgcn_cvt_pk_f32_fp8(kvA.z, false);
            f32x2 va23 = __builtin_amdgcn_cvt_pk_f32_fp8(kvA.z, true);
            f32x2 va45 = __builtin_amdgcn_cvt_pk_f32_fp8(kvA.w, false);
            f32x2 va67 = __builtin_amdgcn_cvt_pk_f32_fp8(kvA.w, true);
            f32x2 vb01 = __builtin_amdgcn_cvt_pk_f32_fp8(kvB.z, false);
            f32x2 vb23 = __builtin_amdgcn_cvt_pk_f32_fp8(kvB.z, true);
            f32x2 vb45 = __builtin_amdgcn_cvt_pk_f32_fp8(kvB.w, false);
            f32x2 vb67 = __builtin_amdgcn_cvt_pk_f32_fp8(kvB.w, true);
            acc[0] = fmaf(acc[0], scale, pe * va01.x);
            acc[1] = fmaf(acc[1], scale, pe * va01.y);
            acc[2] = fmaf(acc[2], scale, pe * va23.x);
            acc[3] = fmaf(acc[3], scale, pe * va23.y);
            acc[4] = fmaf(acc[4], scale, pe * va45.x);
            acc[5] = fmaf(acc[5], scale, pe * va45.y);
            acc[6] = fmaf(acc[6], scale, pe * va67.x);
            acc[7] = fmaf(acc[7], scale, pe * va67.y);
            acc[8] = fmaf(acc[8], scale, pe * vb01.x);
            acc[9] = fmaf(acc[9], scale, pe * vb01.y);
            acc[10] = fmaf(acc[10], scale, pe * vb23.x);
            acc[11] = fmaf(acc[11], scale, pe * vb23.y);
            acc[12] = fmaf(acc[12], scale, pe * vb45.x);
            acc[13] = fmaf(acc[13], scale, pe * vb45.y);
            acc[14] = fmaf(acc[14], scale, pe * vb67.x);
            acc[15] = fmaf(acc[15], scale, pe * vb67.y);
            m = mn;
            if (!haven) break;
            en = en2; sn = sn2; kvA = kvnA; kvB = kvnB;
        }
    }

    // cross-group (8 groups) online-softmax merge
    float mo = __shfl_xor(m, 8);
    float m2 = fmaxf(m, mo);
    mo = __shfl_xor(m2, 16);
    float m3 = fmaxf(m2, mo);
    mo = __shfl_xor(m3, 32);
    float mf = fmaxf(m3, mo);
    float sc = __expf(m - mf);
    den *= sc;
    den += __shfl_xor(den, 8);
    den += __shfl_xor(den, 16);
    den += __shfl_xor(den, 32);
    #pragma unroll
    for (int c = 0; c < 16; ++c) {
        float a = acc[c] * sc;
        a += __shfl_xor(a, 8);
        a += __shfl_xor(a, 16);
        a += __shfl_xor(a, 32);
        acc[c] = a;
    }
    float inv = den > 0.f ? 1.0f / den : 0.f;
    if (g == 0) {
        u16x8 sA = *(const u16x8*)(sb + (size_t)node * DD + j * 8);
        u16x8 sB = *(const u16x8*)(sb + (size_t)node * DD + 64 + j * 8);
        u16x8 oA, oB;
        #pragma unroll
        for (int c = 0; c < 8; ++c) {
            oA[c] = f2bf(fmaxf(fmaf(acc[c], inv, bf2f(sA[c])), 0.f));
            oB[c] = f2bf(fmaxf(fmaf(acc[8 + c], inv, bf2f(sB[c])), 0.f));
        }
        *(u16x8*)(hout + (size_t)node * DD + j * 8) = oA;
        *(u16x8*)(hout + (size_t)node * DD + 64 + j * 8) = oB;
    }
}

// ---------------- global mean pool (h bf16): segmented running sum ----------

__global__ __launch_bounds__(128) void pool_kernel(const unsigned short* __restrict__ h,
                                                   const int* __restrict__ batch,
                                                   float* __restrict__ gsum,
                                                   float* __restrict__ gcnt, int n) {
    __shared__ int bsh[PCHUNK];
    int t = threadIdx.x;
    int node0 = blockIdx.x * PCHUNK;
    int nnodes = min(PCHUNK, n - node0);
    if (t < nnodes) bsh[t] = batch[node0 + t];
    __syncthreads();

    int cur = bsh[0];
    float acc = 0.f;
    int cnt = 0;
    for (int j0 = 0; j0 < nnodes; j0 += 4) {
        int jm = min(4, nnodes - j0);
        float v[4];
        #pragma unroll
        for (int u = 0; u < 4; ++u)
            v[u] = (u < jm) ? bf2f(h[(size_t)(node0 + j0 + u) * DD + t]) : 0.f;
        #pragma unroll
        for (int u = 0; u < 4; ++u) {
            if (u < jm) {
                int g = bsh[j0 + u];
                if (g != cur) {
                    atomicAdd(&gsum[cur * DD + t], acc);
                    if (t == 0) atomicAdd(&gcnt[cur], (float)cnt);
                    acc = 0.f; cnt = 0; cur = g;
                }
                acc += v[u]; ++cnt;
            }
        }
    }
    if (cnt > 0) {
        atomicAdd(&gsum[cur * DD + t], acc);
        if (t == 0) atomicAdd(&gcnt[cur], (float)cnt);
    }
}

// ---------------- FC + log_softmax ----------------

__global__ __launch_bounds__(64) void head_kernel(
    const float* __restrict__ gsum, const float* __restrict__ gcnt,
    const float* __restrict__ wfc, const float* __restrict__ bfc,
    float* __restrict__ out) {
    int g = blockIdx.x;
    int lane = threadIdx.x;
    float cnt = fmaxf(gcnt[g], 1.0f);
    float inv = 1.0f / cnt;
    float p0 = gsum[g * DD + lane] * inv;
    float p1 = gsum[g * DD + lane + 64] * inv;
    __shared__ float logits[NCLS];
    for (int c = 0; c < NCLS; ++c) {
        float partial = p0 * wfc[lane * NCLS + c] + p1 * wfc[(lane + 64) * NCLS + c];
        partial += __shfl_xor(partial, 32);
        partial += __shfl_xor(partial, 16);
        partial += __shfl_xor(partial, 8);
        partial += __shfl_xor(partial, 4);
        partial += __shfl_xor(partial, 2);
        partial += __shfl_xor(partial, 1);
        if (lane == 0) logits[c] = partial + bfc[c];
    }
    __syncthreads();
    if (lane == 0) {
        float mx = logits[0];
        for (int c = 1; c < NCLS; ++c) mx = fmaxf(mx, logits[c]);
        float sum = 0.f;
        for (int c = 0; c < NCLS; ++c) sum += expf(logits[c] - mx);
        float lse = mx + logf(sum);
        for (int c = 0; c < NCLS; ++c) out[g * NCLS + c] = logits[c] - lse;
    }
}

// ---------------- launch ----------------

extern "C" void kernel_launch(void* const* d_in, const int* in_sizes, int n_in,
                              void* d_out, int out_size, void* d_ws, size_t ws_size,
                              hipStream_t stream) {
    const float* x     = (const float*)d_in[0];
    const int*   ei    = (const int*)d_in[1];
    const int*   batch = (const int*)d_in[2];
    const float* Wq = (const float*)d_in[3];
    const float* bq = (const float*)d_in[4];
    const float* Wk = (const float*)d_in[5];
    const float* bk = (const float*)d_in[6];
    const float* Wv = (const float*)d_in[7];
    const float* bv = (const float*)d_in[8];
    const float* Ws = (const float*)d_in[9];
    const float* bs = (const float*)d_in[10];
    const float* Wfc = (const float*)d_in[11];
    const float* bfc = (const float*)d_in[12];
    float* out = (float*)d_out;

    const size_t ND = (size_t)NN * DD;
    unsigned short* hbuf = (unsigned short*)d_ws;   // bf16
    unsigned short* qb  = hbuf + ND;
    unsigned short* sb  = qb + ND;
    unsigned short* wt  = sb + ND;                  // [2][4][128][128] bf16
    unsigned char*  kv8 = (unsigned char*)(wt + 2 * 4 * 16384);  // [NN][256] fp8 packed
    unsigned short* xb  = (unsigned short*)(kv8 + (size_t)NN * 256);  // [NN][128] bf16
    int* bucketcnt = (int*)(xb + ND);
    int* indptr    = bucketcnt + 256;               // [NN+1]
    int* esrc      = indptr + NN + 1;               // [EE]
    int2* bedge    = (int2*)(esrc + EE);            // [NBUK*BSTRIDE]
    float* gsum = (float*)(bedge + NBUK * BSTRIDE);
    float* gcnt = gsum + GG * DD;

    const int* src = ei;
    const int* dst = ei + EE;

    prep_kernel<<<512, 256, 0, stream>>>(Wq, Wk, Wv, Ws, x, xb, wt, bucketcnt, gsum);
    bucket_kernel<<<256, 1024, 0, stream>>>(src, dst, bucketcnt, bedge);
    bsort_kernel<<<NBUK, 1024, 0, stream>>>(bucketcnt, bedge, indptr, esrc);

    for (int l = 0; l < 2; ++l) {
        size_t bo = (size_t)l * DD;
        const unsigned short* wtl = wt + (size_t)l * 4 * 16384;
        gemm_mfma<<<512, 256, 0, stream>>>(
            (l == 0) ? xb : hbuf, wtl, bq + bo, bk + bo, bv + bo, bs + bo,
            qb, sb, kv8);
        attn_kernel<<<(NN + 3) / 4, 256, 0, stream>>>(
            qb, kv8, sb, indptr, esrc, hbuf, NN);
    }

    pool_kernel<<<(NN + PCHUNK - 1) / PCHUNK, 128, 0, stream>>>(hbuf, batch, gsum, gcnt, NN);
    head_kernel<<<GG, 64, 0, stream>>>(gsum, gcnt, Wfc, bfc, out);
}

// Round 8
// 247.919 us; speedup vs baseline: 1.0745x; 1.0745x over previous
//
#include <hip/hip_runtime.h>
#include <math.h>

#define NN 50000
#define EE 600000
#define DD 128
#define GG 64
#define NCLS 10
#define PCHUNK 64
#define NTILE (NN / 16)            // 3125 row-tiles, exact
#define NBUK 196                   // buckets of 256 dst nodes (dst>>8)
#define BSTRIDE 4096               // slots per bucket (mean 3072, sigma 55)
#define EPB ((EE + 255) / 256)     // 2344 edges per pass-1 block

typedef __attribute__((ext_vector_type(8))) __bf16 bf16x8;
typedef __attribute__((ext_vector_type(8))) unsigned short u16x8;
typedef __attribute__((ext_vector_type(4))) float f32x4;
typedef __attribute__((ext_vector_type(2))) float f32x2;

#define LGKM_FENCE() asm volatile("s_waitcnt lgkmcnt(0)" ::: "memory")
#define SCHED_FENCE() __builtin_amdgcn_sched_barrier(0)

__device__ __forceinline__ unsigned short f2bf(float f) {
    unsigned int u = __float_as_uint(f);
    u += 0x7fff + ((u >> 16) & 1);     // round-to-nearest-even
    return (unsigned short)(u >> 16);
}

__device__ __forceinline__ float bf2f(unsigned short h) {
    return __uint_as_float(((unsigned int)h) << 16);
}

// dword-wise bf16 pair unpack: 1 VALU op per element
__device__ __forceinline__ float lo16(unsigned int u) { return __uint_as_float(u << 16); }
__device__ __forceinline__ float hi16(unsigned int u) { return __uint_as_float(u & 0xffff0000u); }

// ------- fused prep: zero bucketcnt/gsum + wt convert + x fp32->bf16 --------

__global__ __launch_bounds__(256) void prep_kernel(
    const float* __restrict__ wq, const float* __restrict__ wk,
    const float* __restrict__ wv, const float* __restrict__ ws,
    const float* __restrict__ x, unsigned short* __restrict__ xb,
    unsigned short* __restrict__ wt,
    int* __restrict__ bucketcnt, float* __restrict__ gsum) {
    int tid = blockIdx.x * 256 + threadIdx.x;
    int TOT = gridDim.x * 256;
    if (tid < 256) bucketcnt[tid] = 0;
    for (int i = tid; i < GG * DD + GG; i += TOT) gsum[i] = 0.f;
    for (int i = tid; i < 2 * 4 * 16384; i += TOT) {
        int k = i & 127;
        int n = (i >> 7) & 127;
        int lm = i >> 14;
        int l = lm >> 2, m = lm & 3;
        const float* w = (m == 0) ? wq : (m == 1) ? wk : (m == 2) ? wv : ws;
        wt[i] = f2bf(w[l * 16384 + k * 128 + n]);
    }
    // x: 50000*128 fp32 -> bf16, 8 elems per thread-iter, fully coalesced
    for (int i = tid; i < NN * DD / 8; i += TOT) {
        const float* px = x + (size_t)i * 8;
        float4 f0 = *(const float4*)px;
        float4 f1 = *(const float4*)(px + 4);
        u16x8 o;
        o[0] = f2bf(f0.x); o[1] = f2bf(f0.y); o[2] = f2bf(f0.z); o[3] = f2bf(f0.w);
        o[4] = f2bf(f1.x); o[5] = f2bf(f1.y); o[6] = f2bf(f1.z); o[7] = f2bf(f1.w);
        *(u16x8*)(xb + (size_t)i * 8) = o;
    }
}

// ---------------- CSR pass 1: bucket by dst>>8 ------------------------------

__global__ __launch_bounds__(1024) void bucket_kernel(
    const int* __restrict__ src, const int* __restrict__ dst,
    int* __restrict__ bucketcnt, int2* __restrict__ bedge) {
    __shared__ int hist[256];
    __shared__ int base[256];
    int t = threadIdx.x;
    if (t < 256) hist[t] = 0;
    __syncthreads();
    int e0 = blockIdx.x * EPB;
    int eend = min(e0 + EPB, EE);

    int b0 = -1, b1 = -1, b2 = -1;
    int sl0 = 0, sl1 = 0, sl2 = 0;
    int s0 = 0, s1 = 0, s2 = 0, d0 = 0, d1 = 0, d2 = 0;
    int i = e0 + t;
    if (i < eend) { d0 = dst[i]; s0 = src[i]; b0 = d0 >> 8; sl0 = atomicAdd(&hist[b0], 1); }
    i += 1024;
    if (i < eend) { d1 = dst[i]; s1 = src[i]; b1 = d1 >> 8; sl1 = atomicAdd(&hist[b1], 1); }
    i += 1024;
    if (i < eend) { d2 = dst[i]; s2 = src[i]; b2 = d2 >> 8; sl2 = atomicAdd(&hist[b2], 1); }
    __syncthreads();

    if (t < 256) {
        int h = hist[t];
        base[t] = h ? atomicAdd(&bucketcnt[t], h) : 0;
    }
    __syncthreads();

    if (b0 >= 0) bedge[b0 * BSTRIDE + base[b0] + sl0] = make_int2(s0, d0);
    if (b1 >= 0) bedge[b1 * BSTRIDE + base[b1] + sl1] = make_int2(s1, d1);
    if (b2 >= 0) bedge[b2 * BSTRIDE + base[b2] + sl2] = make_int2(s2, d2);
}

// ---------------- CSR pass 2: per-bucket node sort -> indptr + esrc ---------

__global__ __launch_bounds__(1024) void bsort_kernel(
    const int* __restrict__ bucketcnt, const int2* __restrict__ bedge,
    int* __restrict__ indptr, int* __restrict__ esrc) {
    __shared__ int buf[256];
    __shared__ int cur[256];
    int b = blockIdx.x;
    int t = threadIdx.x;

    if (t < 256) buf[t] = (t < NBUK) ? bucketcnt[t] : 0;
    __syncthreads();
    if (t < 64) {
        int carry = 0;
        #pragma unroll
        for (int c = 0; c < 4; ++c) {
            int v = buf[c * 64 + t];
            int x = v;
            #pragma unroll
            for (int off = 1; off < 64; off <<= 1) {
                int y = __shfl_up(x, off);
                if (t >= off) x += y;
            }
            cur[c * 64 + t] = carry + x - v;
            carry += __shfl(x, 63);
        }
    }
    __syncthreads();
    int count = buf[b];
    int bstart = cur[b];
    int node0 = b << 8;
    int nn = min(256, NN - node0);
    if (b == 0 && t == 0) indptr[NN] = EE;
    __syncthreads();
    if (t < 256) buf[t] = 0;
    __syncthreads();

    const int2* be = bedge + (size_t)b * BSTRIDE;
    for (int i2 = t; i2 < count; i2 += 1024)
        atomicAdd(&buf[be[i2].y - node0], 1);
    __syncthreads();

    if (t < 64) {
        int carry = 0;
        #pragma unroll
        for (int c = 0; c < 4; ++c) {
            int v = buf[c * 64 + t];
            int x = v;
            #pragma unroll
            for (int off = 1; off < 64; off <<= 1) {
                int y = __shfl_up(x, off);
                if (t >= off) x += y;
            }
            cur[c * 64 + t] = carry + x - v;
            carry += __shfl(x, 63);
        }
    }
    __syncthreads();
    if (t < nn) indptr[node0 + t] = bstart + cur[t];
    __syncthreads();

    for (int i2 = t; i2 < count; i2 += 1024) {
        int2 e = be[i2];
        int slot = atomicAdd(&cur[e.y - node0], 1);
        esrc[bstart + slot] = e.x;
    }
}

// ------- persistent paired-mat MFMA GEMM, fp8 kv epilogue, pipelined --------
// (unchanged from R6; R5 pre-commit: gemm theories exhausted, hands off)

__global__ __launch_bounds__(256, 2) void gemm_mfma(
    const unsigned short* __restrict__ xin,     // bf16 [NN][128]
    const unsigned short* __restrict__ wt,      // [4][128][128] bf16, n-major
    const float* __restrict__ bq, const float* __restrict__ bk,
    const float* __restrict__ bv, const float* __restrict__ bs,
    unsigned short* __restrict__ qb, unsigned short* __restrict__ sb,
    unsigned char* __restrict__ kv8) {
    // [mi][row][col] u16, row stride 136 (272B)
    __shared__ __align__(16) unsigned short stg[2][16][136];

    int wid = threadIdx.x >> 6;        // 0..3
    int lane = threadIdx.x & 63;
    int typeB = blockIdx.x & 1;        // 0: q/s block, 1: k/v block
    int mi = wid >> 1;                 // mat index within type
    int ch = wid & 1;                  // 64-col half
    int mat = typeB ? (mi ? 2 : 1) : (mi ? 3 : 0);
    int wseq = blockIdx.x >> 1;        // 0..255
    int lr = lane & 15, quad = lane >> 4;

    const unsigned short* wm_ = wt + mat * 16384;
    const float* bias = (mat == 0) ? bq : (mat == 1) ? bk : (mat == 2) ? bv : bs;

    bf16x8 bfr[4][4];
    #pragma unroll
    for (int ks = 0; ks < 4; ++ks)
        #pragma unroll
        for (int tn = 0; tn < 4; ++tn)
            bfr[ks][tn] = *(const bf16x8*)(wm_ + (ch * 64 + tn * 16 + lr) * 128
                                               + ks * 32 + quad * 8);
    float bcol[4];
    #pragma unroll
    for (int tn = 0; tn < 4; ++tn) bcol[tn] = bias[ch * 64 + tn * 16 + lr];

    int t = threadIdx.x;
    int rr = t >> 4;                   // epilogue row 0..15
    int cj = t & 15;                   // epilogue chunk 0..15

    bf16x8 bufA[4], bufB[4];

    auto load_t = [&](bf16x8 (&b)[4], int tl) {
        const unsigned short* p = xin + (size_t)(tl * 16 + lr) * DD + quad * 8;
        #pragma unroll
        for (int ks = 0; ks < 4; ++ks)
            b[ks] = *(const bf16x8*)(p + ks * 32);
    };

    auto compute_store = [&](bf16x8 (&b)[4], int tile) {
        int row0 = tile * 16;
        f32x4 acc[4];
        #pragma unroll
        for (int tn = 0; tn < 4; ++tn) acc[tn] = (f32x4){0.f, 0.f, 0.f, 0.f};
        #pragma unroll
        for (int ks = 0; ks < 4; ++ks)
            #pragma unroll
            for (int tn = 0; tn < 4; ++tn)
                acc[tn] = __builtin_amdgcn_mfma_f32_16x16x32_bf16(
                    b[ks], bfr[ks][tn], acc[tn], 0, 0, 0);

        // C/D layout: col = lane&15 (+tn*16), row = quad*4 + reg
        #pragma unroll
        for (int tn = 0; tn < 4; ++tn)
            #pragma unroll
            for (int r = 0; r < 4; ++r)
                stg[mi][quad * 4 + r][ch * 64 + tn * 16 + lr] = f2bf(acc[tn][r] + bcol[tn]);
        SCHED_FENCE();
        LGKM_FENCE();                  // ds_writes visible before signaling
        __builtin_amdgcn_s_barrier();
        SCHED_FENCE();

        if (!typeB) {
            // q + s: 16B/thread each, 4KB contiguous per buffer
            uint4 vq = *(const uint4*)&stg[0][rr][cj * 8];
            *(uint4*)(qb + (size_t)(row0 + rr) * 128 + cj * 8) = vq;
            uint4 vs = *(const uint4*)&stg[1][rr][cj * 8];
            *(uint4*)(sb + (size_t)(row0 + rr) * 128 + cj * 8) = vs;
        } else {
            // kv8 row (256B = 16 chunks): chunk j = [k fp8 8j..8j+7 | v fp8 8j..8j+7]
            uint4 kk = *(const uint4*)&stg[0][rr][cj * 8];
            uint4 vv = *(const uint4*)&stg[1][rr][cj * 8];
            unsigned int w0 = __builtin_amdgcn_cvt_pk_fp8_f32(lo16(kk.x), hi16(kk.x), 0, false);
            w0 = __builtin_amdgcn_cvt_pk_fp8_f32(lo16(kk.y), hi16(kk.y), w0, true);
            unsigned int w1 = __builtin_amdgcn_cvt_pk_fp8_f32(lo16(kk.z), hi16(kk.z), 0, false);
            w1 = __builtin_amdgcn_cvt_pk_fp8_f32(lo16(kk.w), hi16(kk.w), w1, true);
            unsigned int w2 = __builtin_amdgcn_cvt_pk_fp8_f32(lo16(vv.x), hi16(vv.x), 0, false);
            w2 = __builtin_amdgcn_cvt_pk_fp8_f32(lo16(vv.y), hi16(vv.y), w2, true);
            unsigned int w3 = __builtin_amdgcn_cvt_pk_fp8_f32(lo16(vv.z), hi16(vv.z), 0, false);
            w3 = __builtin_amdgcn_cvt_pk_fp8_f32(lo16(vv.w), hi16(vv.w), w3, true);
            *(uint4*)(kv8 + (size_t)(row0 + rr) * 256 + cj * 16) = make_uint4(w0, w1, w2, w3);
        }
        SCHED_FENCE();
        LGKM_FENCE();                  // ds_reads done before stg overwrite
        __builtin_amdgcn_s_barrier();
        SCHED_FENCE();
    };

    int tile = wseq;
    load_t(bufA, tile);
    for (;;) {
        int t2 = tile + 256;
        if (t2 < NTILE) load_t(bufB, t2);       // in flight across barriers
        compute_store(bufA, tile);
        if (t2 >= NTILE) break;
        tile = t2;
        int t3 = tile + 256;
        if (t3 < NTILE) load_t(bufA, t3);
        compute_store(bufB, tile);
        if (t3 >= NTILE) break;
        tile = t3;
    }
}

// ---------------- fused online-softmax attention (fp8 kv) -------------------
// R24: revert to R6 4x16 structure (R7's 8x8 split regressed 35->48us;
// counters showed VALUBusy 70% -> VALU-bound, so CUT VALU WORK instead:
// (a) single-exp online softmax: mn=max(m,score) makes one of the two exps
//     exp(0)=1; compute e=exp(-|score-m|) once and select. Bit-exact.
// (b) packed f32x2 math for q.k dot (4 pk-fma vs 8 fma) and V accumulate
//     (8 pk ops vs 16): cvt_pk_f32_fp8 already yields f32x2; gfx950 has
//     v_pk_fma_f32. Worst case compiler scalarizes -> exactly R6 op count.

__global__ __launch_bounds__(256) void attn_kernel(
    const unsigned short* __restrict__ qb, const unsigned char* __restrict__ kv8,
    const unsigned short* __restrict__ sb,
    const int* __restrict__ indptr, const int* __restrict__ esrc,
    unsigned short* __restrict__ hout, int n) {
    int node = (int)((blockIdx.x * blockDim.x + threadIdx.x) >> 6);
    int lane = threadIdx.x & 63;
    if (node >= n) return;
    int g = lane >> 4, j = lane & 15;

    u16x8 q8 = *(const u16x8*)(qb + (size_t)node * DD + j * 8);
    f32x2 qf2[4];
    #pragma unroll
    for (int c = 0; c < 4; ++c)
        qf2[c] = (f32x2){bf2f(q8[2 * c]), bf2f(q8[2 * c + 1])};

    int beg = indptr[node], end = indptr[node + 1];

    float m = -3.0e38f, den = 0.f;
    f32x2 acc2[4];
    #pragma unroll
    for (int c = 0; c < 4; ++c) acc2[c] = (f32x2){0.f, 0.f};

    int e = beg + g;
    if (e < end) {
        int sidx = esrc[e];
        int en = e + 4;
        int sn = (en < end) ? esrc[en] : 0;          // index 1 ahead (resident)
        uint4 kv = *(const uint4*)(kv8 + (size_t)sidx * 256 + j * 16);
        for (;;) {
            bool haven = en < end;
            int en2 = en + 4;
            int sn2 = (en2 < end) ? esrc[en2] : 0;   // index 2 ahead (loading)
            uint4 kvn;
            if (haven)
                kvn = *(const uint4*)(kv8 + (size_t)sn * 256 + j * 16);
            f32x2 k01 = __builtin_amdgcn_cvt_pk_f32_fp8(kv.x, false);
            f32x2 k23 = __builtin_amdgcn_cvt_pk_f32_fp8(kv.x, true);
            f32x2 k45 = __builtin_amdgcn_cvt_pk_f32_fp8(kv.y, false);
            f32x2 k67 = __builtin_amdgcn_cvt_pk_f32_fp8(kv.y, true);
            f32x2 p2 = k01 * qf2[0];
            p2 = k23 * qf2[1] + p2;
            p2 = k45 * qf2[2] + p2;
            p2 = k67 * qf2[3] + p2;
            float p_ = p2.x + p2.y;
            p_ += __shfl_xor(p_, 8);
            p_ += __shfl_xor(p_, 4);
            p_ += __shfl_xor(p_, 2);
            p_ += __shfl_xor(p_, 1);
            float score = p_ * 0.088388347648318447f;   // 1/sqrt(128)
            float td = score - m;
            bool up = td >= 0.f;
            float ef = __expf(-fabsf(td));              // the one exp needed
            float scale = up ? ef : 1.0f;
            float pe = up ? 1.0f : ef;
            if (up) m = score;
            den = fmaf(den, scale, pe);
            f32x2 sc2 = (f32x2){scale, scale};
            f32x2 pe2 = (f32x2){pe, pe};
            f32x2 v01 = __builtin_amdgcn_cvt_pk_f32_fp8(kv.z, false);
            f32x2 v23 = __builtin_amdgcn_cvt_pk_f32_fp8(kv.z, true);
            f32x2 v45 = __builtin_amdgcn_cvt_pk_f32_fp8(kv.w, false);
            f32x2 v67 = __builtin_amdgcn_cvt_pk_f32_fp8(kv.w, true);
            acc2[0] = acc2[0] * sc2 + pe2 * v01;
            acc2[1] = acc2[1] * sc2 + pe2 * v23;
            acc2[2] = acc2[2] * sc2 + pe2 * v45;
            acc2[3] = acc2[3] * sc2 + pe2 * v67;
            if (!haven) break;
            en = en2; sn = sn2; kv = kvn;
        }
    }

    float mo = __shfl_xor(m, 16);
    float m2 = fmaxf(m, mo);
    mo = __shfl_xor(m2, 32);
    float mf = fmaxf(m2, mo);
    float sc = __expf(m - mf);
    den *= sc;
    den += __shfl_xor(den, 16);
    den += __shfl_xor(den, 32);
    float accf[8];
    #pragma unroll
    for (int c = 0; c < 4; ++c) { accf[2 * c] = acc2[c].x; accf[2 * c + 1] = acc2[c].y; }
    #pragma unroll
    for (int c = 0; c < 8; ++c) {
        float a = accf[c] * sc;
        a += __shfl_xor(a, 16);
        a += __shfl_xor(a, 32);
        accf[c] = a;
    }
    float inv = den > 0.f ? 1.0f / den : 0.f;
    if (g == 0) {
        u16x8 s8 = *(const u16x8*)(sb + (size_t)node * DD + j * 8);
        u16x8 o8;
        #pragma unroll
        for (int c = 0; c < 8; ++c)
            o8[c] = f2bf(fmaxf(fmaf(accf[c], inv, bf2f(s8[c])), 0.f));
        *(u16x8*)(hout + (size_t)node * DD + j * 8) = o8;
    }
}

// ---------------- global mean pool (h bf16): segmented running sum ----------

__global__ __launch_bounds__(128) void pool_kernel(const unsigned short* __restrict__ h,
                                                   const int* __restrict__ batch,
                                                   float* __restrict__ gsum,
                                                   float* __restrict__ gcnt, int n) {
    __shared__ int bsh[PCHUNK];
    int t = threadIdx.x;
    int node0 = blockIdx.x * PCHUNK;
    int nnodes = min(PCHUNK, n - node0);
    if (t < nnodes) bsh[t] = batch[node0 + t];
    __syncthreads();

    int cur = bsh[0];
    float acc = 0.f;
    int cnt = 0;
    for (int j0 = 0; j0 < nnodes; j0 += 4) {
        int jm = min(4, nnodes - j0);
        float v[4];
        #pragma unroll
        for (int u = 0; u < 4; ++u)
            v[u] = (u < jm) ? bf2f(h[(size_t)(node0 + j0 + u) * DD + t]) : 0.f;
        #pragma unroll
        for (int u = 0; u < 4; ++u) {
            if (u < jm) {
                int g = bsh[j0 + u];
                if (g != cur) {
                    atomicAdd(&gsum[cur * DD + t], acc);
                    if (t == 0) atomicAdd(&gcnt[cur], (float)cnt);
                    acc = 0.f; cnt = 0; cur = g;
                }
                acc += v[u]; ++cnt;
            }
        }
    }
    if (cnt > 0) {
        atomicAdd(&gsum[cur * DD + t], acc);
        if (t == 0) atomicAdd(&gcnt[cur], (float)cnt);
    }
}

// ---------------- FC + log_softmax ----------------

__global__ __launch_bounds__(64) void head_kernel(
    const float* __restrict__ gsum, const float* __restrict__ gcnt,
    const float* __restrict__ wfc, const float* __restrict__ bfc,
    float* __restrict__ out) {
    int g = blockIdx.x;
    int lane = threadIdx.x;
    float cnt = fmaxf(gcnt[g], 1.0f);
    float inv = 1.0f / cnt;
    float p0 = gsum[g * DD + lane] * inv;
    float p1 = gsum[g * DD + lane + 64] * inv;
    __shared__ float logits[NCLS];
    for (int c = 0; c < NCLS; ++c) {
        float partial = p0 * wfc[lane * NCLS + c] + p1 * wfc[(lane + 64) * NCLS + c];
        partial += __shfl_xor(partial, 32);
        partial += __shfl_xor(partial, 16);
        partial += __shfl_xor(partial, 8);
        partial += __shfl_xor(partial, 4);
        partial += __shfl_xor(partial, 2);
        partial += __shfl_xor(partial, 1);
        if (lane == 0) logits[c] = partial + bfc[c];
    }
    __syncthreads();
    if (lane == 0) {
        float mx = logits[0];
        for (int c = 1; c < NCLS; ++c) mx = fmaxf(mx, logits[c]);
        float sum = 0.f;
        for (int c = 0; c < NCLS; ++c) sum += expf(logits[c] - mx);
        float lse = mx + logf(sum);
        for (int c = 0; c < NCLS; ++c) out[g * NCLS + c] = logits[c] - lse;
    }
}

// ---------------- launch ----------------

extern "C" void kernel_launch(void* const* d_in, const int* in_sizes, int n_in,
                              void* d_out, int out_size, void* d_ws, size_t ws_size,
                              hipStream_t stream) {
    const float* x     = (const float*)d_in[0];
    const int*   ei    = (const int*)d_in[1];
    const int*   batch = (const int*)d_in[2];
    const float* Wq = (const float*)d_in[3];
    const float* bq = (const float*)d_in[4];
    const float* Wk = (const float*)d_in[5];
    const float* bk = (const float*)d_in[6];
    const float* Wv = (const float*)d_in[7];
    const float* bv = (const float*)d_in[8];
    const float* Ws = (const float*)d_in[9];
    const float* bs = (const float*)d_in[10];
    const float* Wfc = (const float*)d_in[11];
    const float* bfc = (const float*)d_in[12];
    float* out = (float*)d_out;

    const size_t ND = (size_t)NN * DD;
    unsigned short* hbuf = (unsigned short*)d_ws;   // bf16
    unsigned short* qb  = hbuf + ND;
    unsigned short* sb  = qb + ND;
    unsigned short* wt  = sb + ND;                  // [2][4][128][128] bf16
    unsigned char*  kv8 = (unsigned char*)(wt + 2 * 4 * 16384);  // [NN][256] fp8 packed
    unsigned short* xb  = (unsigned short*)(kv8 + (size_t)NN * 256);  // [NN][128] bf16
    int* bucketcnt = (int*)(xb + ND);
    int* indptr    = bucketcnt + 256;               // [NN+1]
    int* esrc      = indptr + NN + 1;               // [EE]
    int2* bedge    = (int2*)(esrc + EE);            // [NBUK*BSTRIDE]
    float* gsum = (float*)(bedge + NBUK * BSTRIDE);
    float* gcnt = gsum + GG * DD;

    const int* src = ei;
    const int* dst = ei + EE;

    prep_kernel<<<512, 256, 0, stream>>>(Wq, Wk, Wv, Ws, x, xb, wt, bucketcnt, gsum);
    bucket_kernel<<<256, 1024, 0, stream>>>(src, dst, bucketcnt, bedge);
    bsort_kernel<<<NBUK, 1024, 0, stream>>>(bucketcnt, bedge, indptr, esrc);

    for (int l = 0; l < 2; ++l) {
        size_t bo = (size_t)l * DD;
        const unsigned short* wtl = wt + (size_t)l * 4 * 16384;
        gemm_mfma<<<512, 256, 0, stream>>>(
            (l == 0) ? xb : hbuf, wtl, bq + bo, bk + bo, bv + bo, bs + bo,
            qb, sb, kv8);
        attn_kernel<<<(NN + 3) / 4, 256, 0, stream>>>(
            qb, kv8, sb, indptr, esrc, hbuf, NN);
    }

    pool_kernel<<<(NN + PCHUNK - 1) / PCHUNK, 128, 0, stream>>>(hbuf, batch, gsum, gcnt, NN);
    head_kernel<<<GG, 64, 0, stream>>>(gsum, gcnt, Wfc, bfc, out);
}